// Round 9
// baseline (369.222 us; speedup 1.0000x reference)
//
#include <hip/hip_runtime.h>
#include <hip/hip_bf16.h>

// ---------- types ----------
typedef unsigned short bfu;                                        // bf16 bit-pattern storage
typedef short          bf16x8 __attribute__((ext_vector_type(8))); // MFMA A/B frag (4 VGPRs)
typedef float          floatx4 __attribute__((ext_vector_type(4)));// MFMA C/D frag
typedef unsigned short bfu4 __attribute__((ext_vector_type(4)));   // 8B packed store
typedef unsigned int   u32x2 __attribute__((ext_vector_type(2)));  // 8B LDS write

__device__ __forceinline__ bfu f2bf(float f) {
    __hip_bfloat16 h = __float2bfloat16(f);   // RNE
    return __builtin_bit_cast(unsigned short, h);
}

// hardware 2^x (no range reduction needed for exp2)
__device__ __forceinline__ float ex2(float x) {
#if __has_builtin(__builtin_amdgcn_exp2f)
    return __builtin_amdgcn_exp2f(x);
#else
    return exp2f(x);
#endif
}

// async global->LDS, 16B per lane; lds base must be wave-uniform (HW adds lane*16)
__device__ __forceinline__ void glds16(const bfu* g, bfu* l) {
    __builtin_amdgcn_global_load_lds(
        (const __attribute__((address_space(1))) unsigned int*)g,
        (__attribute__((address_space(3))) unsigned int*)l, 16, 0, 0);
}

// ---------- problem constants ----------
#define BATCH 2
#define SEQ   2048
#define DM    2048
#define NH    16
#define DKH   128
#define SCALE  0.08838834764831845f   // 1/sqrt(128)
#define SCALEQ 0.1275174245f          // log2(e)/sqrt(128): scores in log2 domain

// =====================================================================
// prep: fused {x f32->bf16 convert} + {Q/K/V weight transpose+convert}.
// grid 8192+3072 = 11264 blocks, 256 thr.  Removes one launch boundary.
// =====================================================================
__global__ __launch_bounds__(256)
void prep(const float* __restrict__ x, bfu* __restrict__ xb,
          const float* __restrict__ WQ, const float* __restrict__ WK,
          const float* __restrict__ WV,
          bfu* __restrict__ WtQ, bfu* __restrict__ WtK, bfu* __restrict__ WtV) {
    __shared__ float tile[64][65];
    const int bid = blockIdx.x;
    if (bid < 8192) {
        // ---- cvt_x path: 4 f32 -> 4 bf16 per thread ----
        const int i = (bid * 256 + threadIdx.x) * 4;
        const float4 v = *(const float4*)(x + i);
        bfu4 p; p[0] = f2bf(v.x); p[1] = f2bf(v.y); p[2] = f2bf(v.z); p[3] = f2bf(v.w);
        *(bfu4*)(xb + i) = p;
        return;
    }
    // ---- tcvt_qkv path: 64x64 transpose tile (was grid (2,32,48)) ----
    const int idx = bid - 8192;
    const int gx = idx & 1, gy = (idx >> 1) & 31, gz = idx >> 6;
    const int p = gz >> 4, h = gz & 15;
    const float* src = ((p == 0) ? WQ : (p == 1) ? WK : WV) + (size_t)h * DM * DKH;
    bfu*         dst = ((p == 0) ? WtQ : (p == 1) ? WtK : WtV) + (size_t)h * DKH * DM;
    const float  s   = (p == 0) ? SCALEQ : 1.0f;
    const int r0 = gy * 64, c0 = gx * 64;
    const int t  = threadIdx.x;
    const int lr = t >> 4;
    const int lc = (t & 15) * 4;
    #pragma unroll
    for (int pp = 0; pp < 4; pp++) {
        const float4 v = *(const float4*)(src + (size_t)(r0 + pp*16 + lr) * DKH + c0 + lc);
        tile[pp*16 + lr][lc + 0] = v.x;
        tile[pp*16 + lr][lc + 1] = v.y;
        tile[pp*16 + lr][lc + 2] = v.z;
        tile[pp*16 + lr][lc + 3] = v.w;
    }
    __syncthreads();
    const int rc = t & 15, cb = t >> 4;
    #pragma unroll
    for (int pp = 0; pp < 4; pp++) {
        const int c = pp*16 + cb;
        bfu4 pk;
        #pragma unroll
        for (int j = 0; j < 4; j++) pk[j] = f2bf(tile[rc*4 + j][c] * s);
        *(bfu4*)(dst + (size_t)(c0 + c) * DM + r0 + rc*4) = pk;
    }
}

// WO transpose+convert: [2048(hk)][2048(d)] -> [d][hk].  grid (32,32)
__global__ __launch_bounds__(256)
void tcvt_wo64(const float* __restrict__ WO, bfu* __restrict__ WtO) {
    __shared__ float tile[64][65];
    const int r0 = blockIdx.y * 64, c0 = blockIdx.x * 64;
    const int t  = threadIdx.x;
    const int lr = t >> 4;
    const int lc = (t & 15) * 4;
    #pragma unroll
    for (int pp = 0; pp < 4; pp++) {
        const float4 v = *(const float4*)(WO + (size_t)(r0 + pp*16 + lr) * DM + c0 + lc);
        tile[pp*16 + lr][lc + 0] = v.x;
        tile[pp*16 + lr][lc + 1] = v.y;
        tile[pp*16 + lr][lc + 2] = v.z;
        tile[pp*16 + lr][lc + 3] = v.w;
    }
    __syncthreads();
    const int rc = t & 15, cb = t >> 4;
    #pragma unroll
    for (int pp = 0; pp < 4; pp++) {
        const int c = pp*16 + cb;
        bfu4 pk;
        #pragma unroll
        for (int j = 0; j < 4; j++) pk[j] = f2bf(tile[rc*4 + j][c]);
        *(bfu4*)(WtO + (size_t)(c0 + c) * DM + r0 + rc*4) = pk;
    }
}

// =====================================================================
// 8-phase GEMM helpers (T2 st_16x32 swizzle, T3/T4 counted vmcnt, T5
// setprio) — unchanged proven bodies.
// =====================================================================
__device__ __forceinline__ void stg_half(const bfu* gbase, bfu* slot,
                                         int wave, int lane, int csw) {
    #pragma unroll
    for (int l = 0; l < 2; l++) {
        const int j = l * 8 + wave;                         // wave-issue id 0..15
        glds16(gbase + (size_t)((j >> 1) * 16 + (lane >> 2)) * DM
                     + (j & 1) * 32 + csw,
               slot + j * 512);
    }
}

__device__ __forceinline__ void ld_b8(bf16x8 (&bv)[4][2], const bfu* slot, int rdo) {
    #pragma unroll
    for (int n = 0; n < 4; n++)
        #pragma unroll
        for (int ks = 0; ks < 2; ks++)
            bv[n][ks] = *(const bf16x8*)&slot[(n * 2 + ks) * 512 + rdo];
}

__device__ __forceinline__ void ld_a8(bf16x8 (&af)[4][2], const bfu* slot, int rdo) {
    #pragma unroll
    for (int m = 0; m < 4; m++)
        #pragma unroll
        for (int ks = 0; ks < 2; ks++)
            af[m][ks] = *(const bf16x8*)&slot[(m * 2 + ks) * 512 + rdo];
}

template<int MH, int NHALF>
__device__ __forceinline__ void mfma16(floatx4 (&acc)[8][4],
                                       const bf16x8 (&af)[4][2],
                                       const bf16x8 (&bv)[4][2]) {
    __builtin_amdgcn_s_setprio(1);
    #pragma unroll
    for (int m = 0; m < 4; m++)
        #pragma unroll
        for (int n = 0; n < 2; n++)
            #pragma unroll
            for (int ks = 0; ks < 2; ks++)
                acc[MH*4 + m][NHALF*2 + n] =
                    __builtin_amdgcn_mfma_f32_16x16x32_bf16(
                        af[m][ks], bv[NHALF*2 + n][ks],
                        acc[MH*4 + m][NHALF*2 + n], 0, 0, 0);
    __builtin_amdgcn_s_setprio(0);
}

#define BARW()                                                      \
    __builtin_amdgcn_s_barrier();                                   \
    asm volatile("s_waitcnt lgkmcnt(0)" ::: "memory");              \
    __builtin_amdgcn_sched_barrier(0)

// =====================================================================
// Fused QKV projection.  grid 512 (1D), block 512 (8 waves).
//   blocks 0..255  : Q+K 8-phase 256^2 (UNCHANGED proven body; one
//                    clean round at 1 block/CU, dispatched first)
//   blocks 256..511: V 2-phase 128x256 tiles (exactly 256 tiles -> one
//                    fill round after QK retires; shared-A staging)
// LDS: 128K (qk8) + 24K (V) = 152K static sum -> 1 block/CU (as today).
// Removes the proj_v launch boundary.
// =====================================================================
__global__ __launch_bounds__(512, 2)
void proj_qkv(const bfu* __restrict__ xb,
              const bfu* __restrict__ WtQ, const bfu* __restrict__ WtK,
              const bfu* __restrict__ WtV,
              const float* __restrict__ bQ, const float* __restrict__ bK,
              const float* __restrict__ bV,
              bfu* __restrict__ Qall, bfu* __restrict__ Kall,
              bfu* __restrict__ Vt) {
    __shared__ __align__(16) bfu As[2][2][8192];   // qk8: [buf][half][128*64]
    __shared__ __align__(16) bfu Bs[2][2][8192];
    __shared__ __align__(16) bfu VAs[4096];        // V: [128][32]
    __shared__ __align__(16) bfu VBs[8192];        // V: [256][32]

    const int bid  = blockIdx.x;
    const int tid  = threadIdx.x;
    const int lane = tid & 63;
    const int wave = tid >> 6;
    const int lrow = lane & 15;
    const int quad = lane >> 4;
    const int rowb = lane >> 2;
    const int colb = (lane & 3) * 8;

    if (bid < 256) {
        // ================= Q+K 8-phase (byte-for-byte R5 body) =========
        const int by = bid >> 4;
        const int p  = by >> 3;
        const bfu*   Wt   = (p == 0) ? WtQ : WtK;
        const float* bias = (p == 0) ? bQ  : bK;
        const float  bscale = (p == 0) ? SCALEQ : 1.0f;

        const int wr   = wave >> 2;            // 0..1 : M half (128 rows)
        const int wc   = wave & 3;             // 0..3 : N quarter (64 cols)
        const size_t m0 = (size_t)(bid & 15) * 256;
        const int    n0 = (by & 7) * 256;

        const int csw = ((lane & 3) * 8) ^ ((lane & 32) ? 16 : 0);
        const int rdo = lrow * 32 + ((quad * 8) ^ ((lrow & 8) ? 16 : 0));

        const bfu* Ab = xb + m0 * DM;
        const bfu* Bb = Wt + (size_t)n0 * DM;

        floatx4 acc[8][4] = {};
        bf16x8 af[4][2], bv[4][2];

#define STAGE_A(tau, h)                                                     \
    if ((tau) < 32) stg_half(Ab + (size_t)((h) * 128) * DM + (tau) * 64,    \
                             &As[(tau) & 1][h][0], wave, lane, csw)
#define STAGE_B(tau, h)                                                     \
    if ((tau) < 32) stg_half(Bb + (size_t)((h) * 128) * DM + (tau) * 64,    \
                             &Bs[(tau) & 1][h][0], wave, lane, csw)

        // ---- prologue: 7 half-tiles ----
        STAGE_B(0, 0); STAGE_B(0, 1); STAGE_A(0, 0); STAGE_A(0, 1);
        STAGE_B(1, 0); STAGE_B(1, 1); STAGE_A(1, 0);
        asm volatile("s_waitcnt vmcnt(6)" ::: "memory");
        __builtin_amdgcn_s_barrier();

        #pragma unroll 1
        for (int i = 0; i < 16; i++) {
            const int t0 = 2 * i;
            // ======== K-tile t0 (buf 0) ========
            ld_b8(bv, &Bs[0][wc >> 1][(wc & 1) * 4096], rdo);
            ld_a8(af, &As[0][wr][0], rdo);
            STAGE_A(t0 + 1, 1);
            BARW();
            mfma16<0, 0>(acc, af, bv);
            __builtin_amdgcn_s_barrier();
            STAGE_B(t0 + 2, 0);
            BARW();
            mfma16<0, 1>(acc, af, bv);
            __builtin_amdgcn_s_barrier();
            ld_a8(af, &As[0][wr][4096], rdo);
            STAGE_B(t0 + 2, 1);
            BARW();
            mfma16<1, 0>(acc, af, bv);
            __builtin_amdgcn_s_barrier();
            STAGE_A(t0 + 2, 0);
            BARW();
            mfma16<1, 1>(acc, af, bv);
            if (i == 15) asm volatile("s_waitcnt vmcnt(0)" ::: "memory");
            else         asm volatile("s_waitcnt vmcnt(6)" ::: "memory");
            __builtin_amdgcn_s_barrier();
            // ======== K-tile t0+1 (buf 1) ========
            ld_b8(bv, &Bs[1][wc >> 1][(wc & 1) * 4096], rdo);
            ld_a8(af, &As[1][wr][0], rdo);
            STAGE_A(t0 + 2, 1);
            BARW();
            mfma16<0, 0>(acc, af, bv);
            __builtin_amdgcn_s_barrier();
            STAGE_B(t0 + 3, 0);
            BARW();
            mfma16<0, 1>(acc, af, bv);
            __builtin_amdgcn_s_barrier();
            ld_a8(af, &As[1][wr][4096], rdo);
            STAGE_B(t0 + 3, 1);
            BARW();
            mfma16<1, 0>(acc, af, bv);
            __builtin_amdgcn_s_barrier();
            STAGE_A(t0 + 3, 0);
            BARW();
            mfma16<1, 1>(acc, af, bv);
            if (i < 15) asm volatile("s_waitcnt vmcnt(6)" ::: "memory");
            __builtin_amdgcn_s_barrier();
        }
#undef STAGE_A
#undef STAGE_B

        // ---- epilogue ----
        bfu* Out = (p == 0) ? Qall : Kall;
        #pragma unroll
        for (int m = 0; m < 8; m++) {
            #pragma unroll
            for (int n = 0; n < 4; n++) {
                const int gn = n0 + wc * 64 + n * 16 + lrow;
                const float bvv = bias[gn] * bscale;
                #pragma unroll
                for (int r = 0; r < 4; r++) {
                    const size_t gm = m0 + wr * 128 + m * 16 + quad * 4 + r;
                    Out[gm * DM + gn] = f2bf(acc[m][n][r] + bvv);
                }
            }
        }
        return;
    }

    // ================= V 2-phase, 128x256 tile (256 tiles) =============
    const int vb = bid - 256;
    const size_t m0 = (size_t)(vb & 31) * 128;     // 32 m-tiles
    const size_t n0 = (size_t)(vb >> 5) * 256;     // 8 n-tiles
    const int mw = (wave & 1) * 64;
    const int nw = (wave >> 1) * 64;               // 0..3 quarters of 256

    floatx4 acc[4][4] = {};

    for (int k0 = 0; k0 < DM; k0 += 32) {
        __syncthreads();
        // 24 chunks (A:8 + B:16) over 8 waves = 3 per wave, shared-A
        #pragma unroll
        for (int j = 0; j < 3; j++) {
            const int c = wave * 3 + j;            // wave-uniform
            if (c < 8) {
                glds16(xb  + (m0 + c*16 + rowb) * DM + k0 + colb, &VAs[c * 512]);
            } else {
                const int c2 = c - 8;
                glds16(WtV + (n0 + c2*16 + rowb) * DM + k0 + colb, &VBs[c2 * 512]);
            }
        }
        __syncthreads();
        bf16x8 af[4], bfr[4];
        #pragma unroll
        for (int t = 0; t < 4; t++) {
            af[t]  = *(const bf16x8*)&VAs[(mw + t*16 + lrow) * 32 + quad * 8];
            bfr[t] = *(const bf16x8*)&VBs[(nw + t*16 + lrow) * 32 + quad * 8];
        }
        #pragma unroll
        for (int mt = 0; mt < 4; mt++)
            #pragma unroll
            for (int nt = 0; nt < 4; nt++)
                acc[mt][nt] = __builtin_amdgcn_mfma_f32_16x16x32_bf16(
                                  af[mt], bfr[nt], acc[mt][nt], 0, 0, 0);
    }

    // transposed epilogue -> Vt[b][h][dk][s]
    #pragma unroll
    for (int mt = 0; mt < 4; mt++) {
        #pragma unroll
        for (int nt = 0; nt < 4; nt++) {
            const int nl = (int)n0 + nw + nt*16 + lrow;
            const float bvv = bV[nl];
            const size_t gm0 = m0 + mw + mt*16 + quad*4;   // 4 consecutive s rows
            const int b = (int)(gm0 >> 11), s = (int)(gm0 & 2047);
            bfu4 pk;
            #pragma unroll
            for (int r = 0; r < 4; r++) pk[r] = f2bf(acc[mt][nt][r] + bvv);
            *(bfu4*)&Vt[((size_t)(b * NH + (nl >> 7)) * DKH + (nl & 127)) * SEQ + s] = pk;
        }
    }
}

// =====================================================================
// causal flash attention — unchanged R8 body (single-buffer, swizzled
// K/V, masked-tail split, exp2 domain, setprio).  grid (32,32), 256 thr
// =====================================================================
__global__ __launch_bounds__(256)
void flash_attn(const bfu* __restrict__ Q, const bfu* __restrict__ K,
                const bfu* __restrict__ Vt, bfu* __restrict__ Z) {
    __shared__ bfu Ks[4][64][32];    // [kc][key][32 k-elems] : 16 KB
    __shared__ bfu Vs[2][128][32];   // [s-half][dk][32 s]    : 16 KB
    __shared__ bfu Ps[4][16][72];    // per wave [q][64 s + 8 pad] : 9 KB

    const int tid  = threadIdx.x;
    const int lane = tid & 63;
    const int wave = tid >> 6;
    const int lrow = lane & 15;
    const int quad = lane >> 4;
    const int hb = blockIdx.x;
    const int h = hb & 15, b = hb >> 4;
    const int qt = 31 - blockIdx.y;            // heavy blocks first
    const int q0w = qt * 64 + wave * 16;
    const int rowb = lane >> 2;
    const int csw  = ((lane & 3) * 8) ^ ((lane & 32) ? 16 : 0);
    const int rq0  = (quad * 8) ^ ((lrow & 8) ? 16 : 0);

    const bfu* Qrow = Q + (size_t)(b * SEQ + q0w + lrow) * DM + h * DKH;
    bf16x8 qf[4];
    #pragma unroll
    for (int kc = 0; kc < 4; kc++)
        qf[kc] = *(const bf16x8*)(Qrow + kc*32 + quad*8);

    floatx4 z[8] = {};
    float l_loc = 0.f;
    const int qg = q0w + lrow;                 // this lane's q row (swapped layout)

    const bfu* Kb = K + (size_t)b * SEQ * DM + h * DKH;
    const bfu* Vb = Vt + (size_t)(b * NH + h) * DKH * SEQ;
    const int ntiles = qt + 1;                 // 64-key tiles, causal

    for (int it = 0; it < ntiles; it++) {
        const int s0 = it * 64;
        __syncthreads();                       // prior iter's LDS reads done
        #pragma unroll
        for (int i = 0; i < 8; i++) {
            const int chunk = wave * 8 + i;    // wave-uniform
            if (chunk < 16) {
                const int kc = chunk >> 2, kg = chunk & 3;
                glds16(Kb + (size_t)(s0 + kg*16 + rowb) * DM + kc*32 + csw,
                       &Ks[kc][kg*16][0]);
            } else {
                const int c2 = chunk - 16;
                const int sh = c2 >> 3, dg = c2 & 7;
                glds16(Vb + (size_t)(dg*16 + rowb) * SEQ + s0 + sh*32 + csw,
                       &Vs[sh][dg*16][0]);
            }
        }
        __syncthreads();                       // staged data visible

        // ---- S^T = K Q^T ----
        floatx4 sc[4];
        __builtin_amdgcn_s_setprio(1);
        #pragma unroll
        for (int st = 0; st < 4; st++) {
            floatx4 a = {};
            #pragma unroll
            for (int kc = 0; kc < 4; kc++) {
                bf16x8 kf = *(const bf16x8*)&Ks[kc][st*16 + lrow][rq0];
                a = __builtin_amdgcn_mfma_f32_16x16x32_bf16(kf, qf[kc], a, 0, 0, 0);
            }
            sc[st] = a;
        }
        __builtin_amdgcn_s_setprio(0);

        // ---- softmax: branch-free interior, masks on diagonal ----
        if (it + 1 < ntiles) {
            #pragma unroll
            for (int st = 0; st < 4; st++) {
                const float p0 = ex2(sc[st][0]);
                const float p1 = ex2(sc[st][1]);
                const float p2 = ex2(sc[st][2]);
                const float p3 = ex2(sc[st][3]);
                l_loc += (p0 + p1) + (p2 + p3);
                u32x2 pk;
                pk[0] = (unsigned)f2bf(p0) | ((unsigned)f2bf(p1) << 16);
                pk[1] = (unsigned)f2bf(p2) | ((unsigned)f2bf(p3) << 16);
                *(u32x2*)&Ps[wave][lrow][st*16 + quad*4] = pk;
            }
        } else {
            #pragma unroll
            for (int st = 0; st < 4; st++) {
                const int sbase = s0 + st*16 + quad*4;
                const float p0 = (sbase + 0 <= qg) ? ex2(sc[st][0]) : 0.f;
                const float p1 = (sbase + 1 <= qg) ? ex2(sc[st][1]) : 0.f;
                const float p2 = (sbase + 2 <= qg) ? ex2(sc[st][2]) : 0.f;
                const float p3 = (sbase + 3 <= qg) ? ex2(sc[st][3]) : 0.f;
                l_loc += (p0 + p1) + (p2 + p3);
                u32x2 pk;
                pk[0] = (unsigned)f2bf(p0) | ((unsigned)f2bf(p1) << 16);
                pk[1] = (unsigned)f2bf(p2) | ((unsigned)f2bf(p3) << 16);
                *(u32x2*)&Ps[wave][lrow][st*16 + quad*4] = pk;
            }
        }

        // ---- O += P V ----
        bf16x8 pf0 = *(const bf16x8*)&Ps[wave][lrow][quad*8];
        bf16x8 pf1 = *(const bf16x8*)&Ps[wave][lrow][32 + quad*8];
        __builtin_amdgcn_s_setprio(1);
        #pragma unroll
        for (int dt = 0; dt < 8; dt++) {
            bf16x8 v0 = *(const bf16x8*)&Vs[0][dt*16 + lrow][rq0];
            z[dt] = __builtin_amdgcn_mfma_f32_16x16x32_bf16(pf0, v0, z[dt], 0, 0, 0);
            bf16x8 v1 = *(const bf16x8*)&Vs[1][dt*16 + lrow][rq0];
            z[dt] = __builtin_amdgcn_mfma_f32_16x16x32_bf16(pf1, v1, z[dt], 0, 0, 0);
        }
        __builtin_amdgcn_s_setprio(0);
    }

    // ---- final l reduce + normalize + store ----
    float L = l_loc;
    L += __shfl_xor(L, 16);
    L += __shfl_xor(L, 32);
    float inv[4];
    #pragma unroll
    for (int r = 0; r < 4; r++)
        inv[r] = 1.0f / __shfl(L, quad*4 + r, 64);
    #pragma unroll
    for (int dt = 0; dt < 8; dt++) {
        #pragma unroll
        for (int r = 0; r < 4; r++) {
            const int qq = q0w + quad*4 + r;
            const int dk = dt*16 + lrow;
            Z[(size_t)(b * SEQ + qq) * DM + h * DKH + dk] = f2bf(z[dt][r] * inv[r]);
        }
    }
}

// =====================================================================
// output projection (m97-style): out_f32 = Zb * WtO^T + bO — unchanged
// =====================================================================
__global__ __launch_bounds__(256)
void out_gemm(const bfu* __restrict__ Zb, const bfu* __restrict__ WtO,
              const float* __restrict__ bO, float* out) {
    __shared__ bfu As[128 * 32];
    __shared__ bfu Bs[128 * 32];
    const int tid  = threadIdx.x;
    const int lane = tid & 63;
    const int wave = tid >> 6;
    const int lrow = lane & 15;
    const int quad = lane >> 4;
    const int mw = (wave & 1) * 64;
    const int nw = (wave >> 1) * 64;
    const size_t m0 = (size_t)blockIdx.x * 128;
    const size_t n0 = (size_t)blockIdx.y * 128;
    const int rowb = lane >> 2, colb = (lane & 3) * 8;

    floatx4 acc[4][4] = {};

    for (int k0 = 0; k0 < DM; k0 += 32) {
        __syncthreads();
        #pragma unroll
        for (int i = 0; i < 2; i++) {
            const int rg = wave * 2 + i;
            glds16(Zb  + (m0 + rg*16 + rowb) * DM + k0 + colb, &As[rg * 512]);
            glds16(WtO + (n0 + rg*16 + rowb) * DM + k0 + colb, &Bs[rg * 512]);
        }
        __syncthreads();
        bf16x8 af[4], bfr[4];
        #pragma unroll
        for (int t = 0; t < 4; t++) {
            af[t]  = *(const bf16x8*)&As[(mw + t*16 + lrow) * 32 + quad * 8];
            bfr[t] = *(const bf16x8*)&Bs[(nw + t*16 + lrow) * 32 + quad * 8];
        }
        #pragma unroll
        for (int mt = 0; mt < 4; mt++)
            #pragma unroll
            for (int nt = 0; nt < 4; nt++)
                acc[mt][nt] = __builtin_amdgcn_mfma_f32_16x16x32_bf16(
                                  af[mt], bfr[nt], acc[mt][nt], 0, 0, 0);
    }

    #pragma unroll
    for (int mt = 0; mt < 4; mt++) {
        #pragma unroll
        for (int nt = 0; nt < 4; nt++) {
            const size_t gn = n0 + nw + nt*16 + lrow;
            const float bv = bO[gn];
            #pragma unroll
            for (int r = 0; r < 4; r++) {
                const size_t gm = m0 + mw + mt*16 + quad*4 + r;
                out[gm * DM + gn] = acc[mt][nt][r] + bv;
            }
        }
    }
}

// =====================================================================
extern "C" void kernel_launch(void* const* d_in, const int* in_sizes, int n_in,
                              void* d_out, int out_size, void* d_ws, size_t ws_size,
                              hipStream_t stream) {
    const float* x  = (const float*)d_in[0];
    const float* WQ = (const float*)d_in[1];
    const float* bQ = (const float*)d_in[2];
    const float* WK = (const float*)d_in[3];
    const float* bK = (const float*)d_in[4];
    const float* WV = (const float*)d_in[5];
    const float* bV = (const float*)d_in[6];
    const float* WO = (const float*)d_in[7];
    const float* bO = (const float*)d_in[8];
    float* out = (float*)d_out;
    bfu* ws  = (bfu*)d_ws;
    bfu* dob = (bfu*)d_out;   // d_out doubles as scratch before out_gemm writes it

    // ws (64 MiB = 33.55M bfu):
    //   ws0: Qall [4096][2048]  -> after flash: WtO [2048][2048]
    //   ws1: Kall [4096][2048]
    //   ws2: Vt   [2][16][128][2048]
    //   ws3: WtV (4.19M) -> after proj: Zb [4096][2048]
    // d_out (16.78M bfu) as early scratch:
    //   xb  = dob[0 .. 8.39M)          (bf16 x)
    //   WtQ = dob[8.39M .. 12.58M)
    //   WtK = dob[12.58M .. 16.78M)
    bfu* Qall = ws;
    bfu* Kall = Qall + 8388608;
    bfu* Vt   = Kall + 8388608;
    bfu* Zb   = Vt   + 8388608;
    bfu* WtV  = Zb;                     // dead before flash writes Zb
    bfu* xb   = dob;
    bfu* WtQ  = dob + 8388608;
    bfu* WtK  = dob + 12582912;

    // 5 launches (was 7): fused prep + fused QKV projection
    prep<<<11264, 256, 0, stream>>>(x, xb, WQ, WK, WV, WtQ, WtK, WtV);

    proj_qkv<<<512, 512, 0, stream>>>(xb, WtQ, WtK, WtV, bQ, bK, bV,
                                      Qall, Kall, Vt);

    flash_attn<<<dim3(32, 32), 256, 0, stream>>>(Qall, Kall, Vt, Zb);

    // Qall dead -> its region becomes WtO (vectorized transpose)
    tcvt_wo64<<<dim3(32, 32), 256, 0, stream>>>(WO, Qall);
    out_gemm<<<dim3(32, 16), 256, 0, stream>>>(Zb, Qall, bO, out);
}

// Round 10
// 358.955 us; speedup vs baseline: 1.0286x; 1.0286x over previous
//
#include <hip/hip_runtime.h>
#include <hip/hip_bf16.h>

// ---------- types ----------
typedef unsigned short bfu;                                        // bf16 bit-pattern storage
typedef short          bf16x8 __attribute__((ext_vector_type(8))); // MFMA A/B frag (4 VGPRs)
typedef float          floatx4 __attribute__((ext_vector_type(4)));// MFMA C/D frag
typedef unsigned short bfu4 __attribute__((ext_vector_type(4)));   // 8B packed store
typedef unsigned int   u32x2 __attribute__((ext_vector_type(2)));  // 8B LDS write

__device__ __forceinline__ bfu f2bf(float f) {
    __hip_bfloat16 h = __float2bfloat16(f);   // RNE
    return __builtin_bit_cast(unsigned short, h);
}

// hardware 2^x (no range reduction needed for exp2)
__device__ __forceinline__ float ex2(float x) {
#if __has_builtin(__builtin_amdgcn_exp2f)
    return __builtin_amdgcn_exp2f(x);
#else
    return exp2f(x);
#endif
}

// async global->LDS, 16B per lane; lds base must be wave-uniform (HW adds lane*16)
__device__ __forceinline__ void glds16(const bfu* g, bfu* l) {
    __builtin_amdgcn_global_load_lds(
        (const __attribute__((address_space(1))) unsigned int*)g,
        (__attribute__((address_space(3))) unsigned int*)l, 16, 0, 0);
}

// ---------- problem constants ----------
#define BATCH 2
#define SEQ   2048
#define DM    2048
#define NH    16
#define DKH   128
#define SCALE  0.08838834764831845f   // 1/sqrt(128)
#define SCALEQ 0.1275174245f          // log2(e)/sqrt(128): scores in log2 domain

// =====================================================================
// prep: fused {x f32->bf16 convert} + {Q/K/V weight transpose+convert}.
// grid 8192+3072 = 11264 blocks, 256 thr.  Homogeneous small blocks --
// safe fusion (unlike R9's proj fusion, which mixed 70us and 35us block
// types in one 1-block/CU round and lost 20us to round-mixing).
// =====================================================================
__global__ __launch_bounds__(256)
void prep(const float* __restrict__ x, bfu* __restrict__ xb,
          const float* __restrict__ WQ, const float* __restrict__ WK,
          const float* __restrict__ WV,
          bfu* __restrict__ WtQ, bfu* __restrict__ WtK, bfu* __restrict__ WtV) {
    __shared__ float tile[64][65];
    const int bid = blockIdx.x;
    if (bid < 8192) {
        // ---- cvt_x path: 4 f32 -> 4 bf16 per thread ----
        const int i = (bid * 256 + threadIdx.x) * 4;
        const float4 v = *(const float4*)(x + i);
        bfu4 p; p[0] = f2bf(v.x); p[1] = f2bf(v.y); p[2] = f2bf(v.z); p[3] = f2bf(v.w);
        *(bfu4*)(xb + i) = p;
        return;
    }
    // ---- tcvt_qkv path: 64x64 transpose tile ----
    const int idx = bid - 8192;
    const int gx = idx & 1, gy = (idx >> 1) & 31, gz = idx >> 6;
    const int p = gz >> 4, h = gz & 15;
    const float* src = ((p == 0) ? WQ : (p == 1) ? WK : WV) + (size_t)h * DM * DKH;
    bfu*         dst = ((p == 0) ? WtQ : (p == 1) ? WtK : WtV) + (size_t)h * DKH * DM;
    const float  s   = (p == 0) ? SCALEQ : 1.0f;
    const int r0 = gy * 64, c0 = gx * 64;
    const int t  = threadIdx.x;
    const int lr = t >> 4;
    const int lc = (t & 15) * 4;
    #pragma unroll
    for (int pp = 0; pp < 4; pp++) {
        const float4 v = *(const float4*)(src + (size_t)(r0 + pp*16 + lr) * DKH + c0 + lc);
        tile[pp*16 + lr][lc + 0] = v.x;
        tile[pp*16 + lr][lc + 1] = v.y;
        tile[pp*16 + lr][lc + 2] = v.z;
        tile[pp*16 + lr][lc + 3] = v.w;
    }
    __syncthreads();
    const int rc = t & 15, cb = t >> 4;
    #pragma unroll
    for (int pp = 0; pp < 4; pp++) {
        const int c = pp*16 + cb;
        bfu4 pk;
        #pragma unroll
        for (int j = 0; j < 4; j++) pk[j] = f2bf(tile[rc*4 + j][c] * s);
        *(bfu4*)(dst + (size_t)(c0 + c) * DM + r0 + rc*4) = pk;
    }
}

// WO transpose+convert: [2048(hk)][2048(d)] -> [d][hk].  grid (32,32)
__global__ __launch_bounds__(256)
void tcvt_wo64(const float* __restrict__ WO, bfu* __restrict__ WtO) {
    __shared__ float tile[64][65];
    const int r0 = blockIdx.y * 64, c0 = blockIdx.x * 64;
    const int t  = threadIdx.x;
    const int lr = t >> 4;
    const int lc = (t & 15) * 4;
    #pragma unroll
    for (int pp = 0; pp < 4; pp++) {
        const float4 v = *(const float4*)(WO + (size_t)(r0 + pp*16 + lr) * DM + c0 + lc);
        tile[pp*16 + lr][lc + 0] = v.x;
        tile[pp*16 + lr][lc + 1] = v.y;
        tile[pp*16 + lr][lc + 2] = v.z;
        tile[pp*16 + lr][lc + 3] = v.w;
    }
    __syncthreads();
    const int rc = t & 15, cb = t >> 4;
    #pragma unroll
    for (int pp = 0; pp < 4; pp++) {
        const int c = pp*16 + cb;
        bfu4 pk;
        #pragma unroll
        for (int j = 0; j < 4; j++) pk[j] = f2bf(tile[rc*4 + j][c]);
        *(bfu4*)(WtO + (size_t)(c0 + c) * DM + r0 + rc*4) = pk;
    }
}

// =====================================================================
// 8-phase GEMM helpers (T2 st_16x32 swizzle, T3/T4 counted vmcnt, T5
// setprio) — unchanged proven bodies.
// =====================================================================
__device__ __forceinline__ void stg_half(const bfu* gbase, bfu* slot,
                                         int wave, int lane, int csw) {
    #pragma unroll
    for (int l = 0; l < 2; l++) {
        const int j = l * 8 + wave;                         // wave-issue id 0..15
        glds16(gbase + (size_t)((j >> 1) * 16 + (lane >> 2)) * DM
                     + (j & 1) * 32 + csw,
               slot + j * 512);
    }
}

__device__ __forceinline__ void ld_b8(bf16x8 (&bv)[4][2], const bfu* slot, int rdo) {
    #pragma unroll
    for (int n = 0; n < 4; n++)
        #pragma unroll
        for (int ks = 0; ks < 2; ks++)
            bv[n][ks] = *(const bf16x8*)&slot[(n * 2 + ks) * 512 + rdo];
}

__device__ __forceinline__ void ld_a8(bf16x8 (&af)[4][2], const bfu* slot, int rdo) {
    #pragma unroll
    for (int m = 0; m < 4; m++)
        #pragma unroll
        for (int ks = 0; ks < 2; ks++)
            af[m][ks] = *(const bf16x8*)&slot[(m * 2 + ks) * 512 + rdo];
}

template<int MH, int NHALF>
__device__ __forceinline__ void mfma16(floatx4 (&acc)[8][4],
                                       const bf16x8 (&af)[4][2],
                                       const bf16x8 (&bv)[4][2]) {
    __builtin_amdgcn_s_setprio(1);
    #pragma unroll
    for (int m = 0; m < 4; m++)
        #pragma unroll
        for (int n = 0; n < 2; n++)
            #pragma unroll
            for (int ks = 0; ks < 2; ks++)
                acc[MH*4 + m][NHALF*2 + n] =
                    __builtin_amdgcn_mfma_f32_16x16x32_bf16(
                        af[m][ks], bv[NHALF*2 + n][ks],
                        acc[MH*4 + m][NHALF*2 + n], 0, 0, 0);
    __builtin_amdgcn_s_setprio(0);
}

#define BARW()                                                      \
    __builtin_amdgcn_s_barrier();                                   \
    asm volatile("s_waitcnt lgkmcnt(0)" ::: "memory");              \
    __builtin_amdgcn_sched_barrier(0)

// =====================================================================
// Q+K projection, 256^2 8-phase: grid (16, 16) = EXACTLY 256 blocks
// (one clean round at 1 block/CU — R8-proven, 69.5us, 0 conflicts)
// =====================================================================
__global__ __launch_bounds__(512, 2)
void proj_qk8(const bfu* __restrict__ xb,
              const bfu* __restrict__ WtQ, const bfu* __restrict__ WtK,
              const float* __restrict__ bQ, const float* __restrict__ bK,
              bfu* __restrict__ Qall, bfu* __restrict__ Kall) {
    __shared__ __align__(16) bfu As[2][2][8192];   // [buf][half][128*64]
    __shared__ __align__(16) bfu Bs[2][2][8192];

    const int p = blockIdx.y >> 3;
    const bfu*   Wt   = (p == 0) ? WtQ : WtK;
    const float* bias = (p == 0) ? bQ  : bK;
    const float  bscale = (p == 0) ? SCALEQ : 1.0f;

    const int tid  = threadIdx.x;
    const int lane = tid & 63;
    const int wave = tid >> 6;
    const int lrow = lane & 15;
    const int quad = lane >> 4;
    const int wr   = wave >> 2;            // 0..1 : M half (128 rows)
    const int wc   = wave & 3;             // 0..3 : N quarter (64 cols)
    const size_t m0 = (size_t)blockIdx.x * 256;
    const int    n0 = (int)(blockIdx.y & 7) * 256;

    const int csw = ((lane & 3) * 8) ^ ((lane & 32) ? 16 : 0);
    const int rdo = lrow * 32 + ((quad * 8) ^ ((lrow & 8) ? 16 : 0));

    const bfu* Ab = xb + m0 * DM;
    const bfu* Bb = Wt + (size_t)n0 * DM;

    floatx4 acc[8][4] = {};
    bf16x8 af[4][2], bv[4][2];

#define STAGE_A(tau, h)                                                     \
    if ((tau) < 32) stg_half(Ab + (size_t)((h) * 128) * DM + (tau) * 64,    \
                             &As[(tau) & 1][h][0], wave, lane, csw)
#define STAGE_B(tau, h)                                                     \
    if ((tau) < 32) stg_half(Bb + (size_t)((h) * 128) * DM + (tau) * 64,    \
                             &Bs[(tau) & 1][h][0], wave, lane, csw)

    // ---- prologue: 7 half-tiles (K-tile 0 + 3/4 of K-tile 1) ----
    STAGE_B(0, 0); STAGE_B(0, 1); STAGE_A(0, 0); STAGE_A(0, 1);
    STAGE_B(1, 0); STAGE_B(1, 1); STAGE_A(1, 0);
    asm volatile("s_waitcnt vmcnt(6)" ::: "memory");
    __builtin_amdgcn_s_barrier();

    #pragma unroll 1
    for (int i = 0; i < 16; i++) {
        const int t0 = 2 * i;
        // ======== K-tile t0 (buf 0) ========
        ld_b8(bv, &Bs[0][wc >> 1][(wc & 1) * 4096], rdo);
        ld_a8(af, &As[0][wr][0], rdo);
        STAGE_A(t0 + 1, 1);
        BARW();
        mfma16<0, 0>(acc, af, bv);
        __builtin_amdgcn_s_barrier();
        STAGE_B(t0 + 2, 0);
        BARW();
        mfma16<0, 1>(acc, af, bv);
        __builtin_amdgcn_s_barrier();
        ld_a8(af, &As[0][wr][4096], rdo);
        STAGE_B(t0 + 2, 1);
        BARW();
        mfma16<1, 0>(acc, af, bv);
        __builtin_amdgcn_s_barrier();
        STAGE_A(t0 + 2, 0);
        BARW();
        mfma16<1, 1>(acc, af, bv);
        if (i == 15) asm volatile("s_waitcnt vmcnt(0)" ::: "memory");
        else         asm volatile("s_waitcnt vmcnt(6)" ::: "memory");
        __builtin_amdgcn_s_barrier();
        // ======== K-tile t0+1 (buf 1) ========
        ld_b8(bv, &Bs[1][wc >> 1][(wc & 1) * 4096], rdo);
        ld_a8(af, &As[1][wr][0], rdo);
        STAGE_A(t0 + 2, 1);
        BARW();
        mfma16<0, 0>(acc, af, bv);
        __builtin_amdgcn_s_barrier();
        STAGE_B(t0 + 3, 0);
        BARW();
        mfma16<0, 1>(acc, af, bv);
        __builtin_amdgcn_s_barrier();
        ld_a8(af, &As[1][wr][4096], rdo);
        STAGE_B(t0 + 3, 1);
        BARW();
        mfma16<1, 0>(acc, af, bv);
        __builtin_amdgcn_s_barrier();
        STAGE_A(t0 + 3, 0);
        BARW();
        mfma16<1, 1>(acc, af, bv);
        if (i < 15) asm volatile("s_waitcnt vmcnt(6)" ::: "memory");
        __builtin_amdgcn_s_barrier();
    }
#undef STAGE_A
#undef STAGE_B

    // ---- epilogue (C/D: col = lane&15 -> n, row = quad*4+r -> m) ----
    bfu* Out = (p == 0) ? Qall : Kall;
    #pragma unroll
    for (int m = 0; m < 8; m++) {
        #pragma unroll
        for (int n = 0; n < 4; n++) {
            const int gn = n0 + wc * 64 + n * 16 + lrow;
            const float bvv = bias[gn] * bscale;
            #pragma unroll
            for (int r = 0; r < 4; r++) {
                const size_t gm = m0 + wr * 128 + m * 16 + quad * 4 + r;
                Out[gm * DM + gn] = f2bf(acc[m][n][r] + bvv);
            }
        }
    }
}

// =====================================================================
// V projection, 2-phase 128^2 (m97-style): Vt[b][h][dk][s] epilogue.
// grid (32,16), block 256 — R8-proven separate launch
// =====================================================================
__global__ __launch_bounds__(256)
void proj_v(const bfu* __restrict__ xb, const bfu* __restrict__ WtV,
            const float* __restrict__ bV, bfu* __restrict__ Vt) {
    __shared__ bfu As[128 * 32];
    __shared__ bfu Bs[128 * 32];
    const int tid  = threadIdx.x;
    const int lane = tid & 63;
    const int wave = tid >> 6;
    const int lrow = lane & 15;
    const int quad = lane >> 4;
    const int mw = (wave & 1) * 64;
    const int nw = (wave >> 1) * 64;
    const size_t m0 = (size_t)blockIdx.x * 128;
    const size_t n0 = (size_t)blockIdx.y * 128;
    const int rowb = lane >> 2;          // 16-row group offset
    const int colb = (lane & 3) * 8;     // k-offset (elems)

    floatx4 acc[4][4] = {};

    for (int k0 = 0; k0 < DM; k0 += 32) {
        __syncthreads();
        #pragma unroll
        for (int i = 0; i < 2; i++) {
            const int rg = wave * 2 + i;    // 0..7 : 16-row groups
            glds16(xb  + (m0 + rg*16 + rowb) * DM + k0 + colb, &As[rg * 512]);
            glds16(WtV + (n0 + rg*16 + rowb) * DM + k0 + colb, &Bs[rg * 512]);
        }
        __syncthreads();
        bf16x8 af[4], bfr[4];
        #pragma unroll
        for (int t = 0; t < 4; t++) {
            af[t]  = *(const bf16x8*)&As[(mw + t*16 + lrow) * 32 + quad * 8];
            bfr[t] = *(const bf16x8*)&Bs[(nw + t*16 + lrow) * 32 + quad * 8];
        }
        #pragma unroll
        for (int mt = 0; mt < 4; mt++)
            #pragma unroll
            for (int nt = 0; nt < 4; nt++)
                acc[mt][nt] = __builtin_amdgcn_mfma_f32_16x16x32_bf16(
                                  af[mt], bfr[nt], acc[mt][nt], 0, 0, 0);
    }

    // transposed epilogue -> Vt[b][h][dk][s]
    #pragma unroll
    for (int mt = 0; mt < 4; mt++) {
        #pragma unroll
        for (int nt = 0; nt < 4; nt++) {
            const int nl = (int)n0 + nw + nt*16 + lrow;
            const float bvv = bV[nl];
            const size_t gm0 = m0 + mw + mt*16 + quad*4;   // 4 consecutive s rows
            const int b = (int)(gm0 >> 11), s = (int)(gm0 & 2047);
            bfu4 pk;
            #pragma unroll
            for (int r = 0; r < 4; r++) pk[r] = f2bf(acc[mt][nt][r] + bvv);
            *(bfu4*)&Vt[((size_t)(b * NH + (nl >> 7)) * DKH + (nl & 127)) * SEQ + s] = pk;
        }
    }
}

// =====================================================================
// causal flash attention — R8-proven body (single-buffer, swizzled K/V,
// masked-tail split, exp2 domain, setprio).  grid (32,32), 256 thr
// =====================================================================
__global__ __launch_bounds__(256)
void flash_attn(const bfu* __restrict__ Q, const bfu* __restrict__ K,
                const bfu* __restrict__ Vt, bfu* __restrict__ Z) {
    __shared__ bfu Ks[4][64][32];    // [kc][key][32 k-elems] : 16 KB
    __shared__ bfu Vs[2][128][32];   // [s-half][dk][32 s]    : 16 KB
    __shared__ bfu Ps[4][16][72];    // per wave [q][64 s + 8 pad] : 9 KB

    const int tid  = threadIdx.x;
    const int lane = tid & 63;
    const int wave = tid >> 6;
    const int lrow = lane & 15;
    const int quad = lane >> 4;
    const int hb = blockIdx.x;
    const int h = hb & 15, b = hb >> 4;
    const int qt = 31 - blockIdx.y;            // heavy blocks first
    const int q0w = qt * 64 + wave * 16;
    const int rowb = lane >> 2;
    const int csw  = ((lane & 3) * 8) ^ ((lane & 32) ? 16 : 0);
    const int rq0  = (quad * 8) ^ ((lrow & 8) ? 16 : 0);

    const bfu* Qrow = Q + (size_t)(b * SEQ + q0w + lrow) * DM + h * DKH;
    bf16x8 qf[4];
    #pragma unroll
    for (int kc = 0; kc < 4; kc++)
        qf[kc] = *(const bf16x8*)(Qrow + kc*32 + quad*8);

    floatx4 z[8] = {};
    float l_loc = 0.f;
    const int qg = q0w + lrow;                 // this lane's q row (swapped layout)

    const bfu* Kb = K + (size_t)b * SEQ * DM + h * DKH;
    const bfu* Vb = Vt + (size_t)(b * NH + h) * DKH * SEQ;
    const int ntiles = qt + 1;                 // 64-key tiles, causal

    for (int it = 0; it < ntiles; it++) {
        const int s0 = it * 64;
        __syncthreads();                       // prior iter's LDS reads done
        #pragma unroll
        for (int i = 0; i < 8; i++) {
            const int chunk = wave * 8 + i;    // wave-uniform
            if (chunk < 16) {
                const int kc = chunk >> 2, kg = chunk & 3;
                glds16(Kb + (size_t)(s0 + kg*16 + rowb) * DM + kc*32 + csw,
                       &Ks[kc][kg*16][0]);
            } else {
                const int c2 = chunk - 16;
                const int sh = c2 >> 3, dg = c2 & 7;
                glds16(Vb + (size_t)(dg*16 + rowb) * SEQ + s0 + sh*32 + csw,
                       &Vs[sh][dg*16][0]);
            }
        }
        __syncthreads();                       // staged data visible

        // ---- S^T = K Q^T ----
        floatx4 sc[4];
        __builtin_amdgcn_s_setprio(1);
        #pragma unroll
        for (int st = 0; st < 4; st++) {
            floatx4 a = {};
            #pragma unroll
            for (int kc = 0; kc < 4; kc++) {
                bf16x8 kf = *(const bf16x8*)&Ks[kc][st*16 + lrow][rq0];
                a = __builtin_amdgcn_mfma_f32_16x16x32_bf16(kf, qf[kc], a, 0, 0, 0);
            }
            sc[st] = a;
        }
        __builtin_amdgcn_s_setprio(0);

        // ---- softmax: branch-free interior, masks on diagonal ----
        if (it + 1 < ntiles) {
            #pragma unroll
            for (int st = 0; st < 4; st++) {
                const float p0 = ex2(sc[st][0]);
                const float p1 = ex2(sc[st][1]);
                const float p2 = ex2(sc[st][2]);
                const float p3 = ex2(sc[st][3]);
                l_loc += (p0 + p1) + (p2 + p3);
                u32x2 pk;
                pk[0] = (unsigned)f2bf(p0) | ((unsigned)f2bf(p1) << 16);
                pk[1] = (unsigned)f2bf(p2) | ((unsigned)f2bf(p3) << 16);
                *(u32x2*)&Ps[wave][lrow][st*16 + quad*4] = pk;
            }
        } else {
            #pragma unroll
            for (int st = 0; st < 4; st++) {
                const int sbase = s0 + st*16 + quad*4;
                const float p0 = (sbase + 0 <= qg) ? ex2(sc[st][0]) : 0.f;
                const float p1 = (sbase + 1 <= qg) ? ex2(sc[st][1]) : 0.f;
                const float p2 = (sbase + 2 <= qg) ? ex2(sc[st][2]) : 0.f;
                const float p3 = (sbase + 3 <= qg) ? ex2(sc[st][3]) : 0.f;
                l_loc += (p0 + p1) + (p2 + p3);
                u32x2 pk;
                pk[0] = (unsigned)f2bf(p0) | ((unsigned)f2bf(p1) << 16);
                pk[1] = (unsigned)f2bf(p2) | ((unsigned)f2bf(p3) << 16);
                *(u32x2*)&Ps[wave][lrow][st*16 + quad*4] = pk;
            }
        }

        // ---- O += P V ----
        bf16x8 pf0 = *(const bf16x8*)&Ps[wave][lrow][quad*8];
        bf16x8 pf1 = *(const bf16x8*)&Ps[wave][lrow][32 + quad*8];
        __builtin_amdgcn_s_setprio(1);
        #pragma unroll
        for (int dt = 0; dt < 8; dt++) {
            bf16x8 v0 = *(const bf16x8*)&Vs[0][dt*16 + lrow][rq0];
            z[dt] = __builtin_amdgcn_mfma_f32_16x16x32_bf16(pf0, v0, z[dt], 0, 0, 0);
            bf16x8 v1 = *(const bf16x8*)&Vs[1][dt*16 + lrow][rq0];
            z[dt] = __builtin_amdgcn_mfma_f32_16x16x32_bf16(pf1, v1, z[dt], 0, 0, 0);
        }
        __builtin_amdgcn_s_setprio(0);
    }

    // ---- final l reduce + normalize + store ----
    float L = l_loc;
    L += __shfl_xor(L, 16);
    L += __shfl_xor(L, 32);
    float inv[4];
    #pragma unroll
    for (int r = 0; r < 4; r++)
        inv[r] = 1.0f / __shfl(L, quad*4 + r, 64);
    #pragma unroll
    for (int dt = 0; dt < 8; dt++) {
        #pragma unroll
        for (int r = 0; r < 4; r++) {
            const int qq = q0w + quad*4 + r;
            const int dk = dt*16 + lrow;
            Z[(size_t)(b * SEQ + qq) * DM + h * DKH + dk] = f2bf(z[dt][r] * inv[r]);
        }
    }
}

// =====================================================================
// output projection (m97-style): out_f32 = Zb * WtO^T + bO — unchanged
// =====================================================================
__global__ __launch_bounds__(256)
void out_gemm(const bfu* __restrict__ Zb, const bfu* __restrict__ WtO,
              const float* __restrict__ bO, float* out) {
    __shared__ bfu As[128 * 32];
    __shared__ bfu Bs[128 * 32];
    const int tid  = threadIdx.x;
    const int lane = tid & 63;
    const int wave = tid >> 6;
    const int lrow = lane & 15;
    const int quad = lane >> 4;
    const int mw = (wave & 1) * 64;
    const int nw = (wave >> 1) * 64;
    const size_t m0 = (size_t)blockIdx.x * 128;
    const size_t n0 = (size_t)blockIdx.y * 128;
    const int rowb = lane >> 2, colb = (lane & 3) * 8;

    floatx4 acc[4][4] = {};

    for (int k0 = 0; k0 < DM; k0 += 32) {
        __syncthreads();
        #pragma unroll
        for (int i = 0; i < 2; i++) {
            const int rg = wave * 2 + i;
            glds16(Zb  + (m0 + rg*16 + rowb) * DM + k0 + colb, &As[rg * 512]);
            glds16(WtO + (n0 + rg*16 + rowb) * DM + k0 + colb, &Bs[rg * 512]);
        }
        __syncthreads();
        bf16x8 af[4], bfr[4];
        #pragma unroll
        for (int t = 0; t < 4; t++) {
            af[t]  = *(const bf16x8*)&As[(mw + t*16 + lrow) * 32 + quad * 8];
            bfr[t] = *(const bf16x8*)&Bs[(nw + t*16 + lrow) * 32 + quad * 8];
        }
        #pragma unroll
        for (int mt = 0; mt < 4; mt++)
            #pragma unroll
            for (int nt = 0; nt < 4; nt++)
                acc[mt][nt] = __builtin_amdgcn_mfma_f32_16x16x32_bf16(
                                  af[mt], bfr[nt], acc[mt][nt], 0, 0, 0);
    }

    #pragma unroll
    for (int mt = 0; mt < 4; mt++) {
        #pragma unroll
        for (int nt = 0; nt < 4; nt++) {
            const size_t gn = n0 + nw + nt*16 + lrow;
            const float bv = bO[gn];
            #pragma unroll
            for (int r = 0; r < 4; r++) {
                const size_t gm = m0 + mw + mt*16 + quad*4 + r;
                out[gm * DM + gn] = acc[mt][nt][r] + bv;
            }
        }
    }
}

// =====================================================================
extern "C" void kernel_launch(void* const* d_in, const int* in_sizes, int n_in,
                              void* d_out, int out_size, void* d_ws, size_t ws_size,
                              hipStream_t stream) {
    const float* x  = (const float*)d_in[0];
    const float* WQ = (const float*)d_in[1];
    const float* bQ = (const float*)d_in[2];
    const float* WK = (const float*)d_in[3];
    const float* bK = (const float*)d_in[4];
    const float* WV = (const float*)d_in[5];
    const float* bV = (const float*)d_in[6];
    const float* WO = (const float*)d_in[7];
    const float* bO = (const float*)d_in[8];
    float* out = (float*)d_out;
    bfu* ws  = (bfu*)d_ws;
    bfu* dob = (bfu*)d_out;   // d_out doubles as scratch before out_gemm writes it

    // ws (64 MiB = 33.55M bfu):
    //   ws0: Qall [4096][2048]  -> after flash: WtO [2048][2048]
    //   ws1: Kall [4096][2048]
    //   ws2: Vt   [2][16][128][2048]
    //   ws3: WtV (4.19M) -> after proj: Zb [4096][2048]
    // d_out (16.78M bfu) as early scratch:
    //   xb  = dob[0 .. 8.39M)          (bf16 x)
    //   WtQ = dob[8.39M .. 12.58M)
    //   WtK = dob[12.58M .. 16.78M)
    bfu* Qall = ws;
    bfu* Kall = Qall + 8388608;
    bfu* Vt   = Kall + 8388608;
    bfu* Zb   = Vt   + 8388608;
    bfu* WtV  = Zb;                     // dead before flash writes Zb
    bfu* xb   = dob;
    bfu* WtQ  = dob + 8388608;
    bfu* WtK  = dob + 12582912;

    // 6 launches: fused prep, then R8-proven split projection pipeline
    prep<<<11264, 256, 0, stream>>>(x, xb, WQ, WK, WV, WtQ, WtK, WtV);

    proj_qk8<<<dim3(16, 16), 512, 0, stream>>>(xb, WtQ, WtK, bQ, bK, Qall, Kall);
    proj_v<<<dim3(32, 16), 256, 0, stream>>>(xb, WtV, bV, Vt);

    flash_attn<<<dim3(32, 32), 256, 0, stream>>>(Qall, Kall, Vt, Zb);

    // Qall dead -> its region becomes WtO (vectorized transpose)
    tcvt_wo64<<<dim3(32, 32), 256, 0, stream>>>(WO, Qall);
    out_gemm<<<dim3(32, 16), 256, 0, stream>>>(Zb, Qall, bO, out);
}